// Round 12
// baseline (135.939 us; speedup 1.0000x reference)
//
#include <hip/hip_runtime.h>

#define DIM 64
#define BIN_SHIFT 7                  // 128 nodes per bin
#define NODES_PER_BIN 128
#define MAX_BINS 1024                // ceil(100000/128)=782 <= 1024
#define BIN_CAP 2048                 // mean 1279, sigma ~36 -> 21-sigma margin
#define CHUNK_EDGES 4096             // edges per scatter block (R11-proven)
#define SCATTER_THREADS 1024         // 4 edges/thread (R11-proven)
#define GEMM_ROWS 128                // rows per gemm block == nodes per bin
#define GCUR_STRIDE 16               // one cacheline per reservation counter

// ws layout (256-aligned):
// gcur[MAX_BINS*16] | pairs[nbins*BIN_CAP+64] | h[(N+1)*64] bf16
//
// Pipeline (1 memset + 3 dispatches):
//   memset gcur
//   K1 scatter: bin scatter, 1024thr x 4096 edges; gcur strided per-line
//   K2 deg_gemm: bin-degree hist in LDS -> sdinv -> MFMA gemm,
//                h = bf16((x @ W^T) * dinv[row])
//   K3 aggregate: LDS counting-sort pairs by dst-local -> contiguous runs ->
//                 fp32 REGISTER accumulation, zero atomics, deg/dinv local

using bf16x8 = __attribute__((ext_vector_type(8))) short;
using f32x4  = __attribute__((ext_vector_type(4))) float;

__device__ __forceinline__ unsigned short f2bf(float f) {
    unsigned u = __float_as_uint(f);
    u += 0x7fffu + ((u >> 16) & 1u);     // round-to-nearest-even
    return (unsigned short)(u >> 16);
}
__device__ __forceinline__ float bf2f(unsigned short u) {
    return __uint_as_float((unsigned)u << 16);
}

// K1: scatter packed (src<<7 | dst&127) into dst-bins.  1024 threads, 4
// edges/thread; one reservation atomic per (block,bin), strided per-line.
__global__ __launch_bounds__(SCATTER_THREADS) void bin_scatter_kernel(
    const void* __restrict__ ei, int* __restrict__ gcur,
    int* __restrict__ pairs, int E, int nbins) {
    __shared__ int h1[MAX_BINS];
    __shared__ int base[MAX_BINS];
    __shared__ int s_notz;
    int tid = threadIdx.x;
    if (tid == 0) s_notz = 0;
    for (int i = tid; i < nbins; i += SCATTER_THREADS) h1[i] = 0;
    __syncthreads();
    if (((const int*)ei)[2 * tid + 1] != 0) s_notz = 1;   // benign race (same value)
    __syncthreads();
    int is64 = (s_notz == 0);
    int chunk = blockIdx.x * CHUNK_EDGES;

    int ss[CHUNK_EDGES / SCATTER_THREADS], dd[CHUNK_EDGES / SCATTER_THREADS];
#pragma unroll
    for (int k = 0; k < CHUNK_EDGES / SCATTER_THREADS; ++k) {
        int i = chunk + k * SCATTER_THREADS + tid;
        if (i < E) {
            int s, d;
            if (is64) {
                s = (int)((const long long*)ei)[i];
                d = (int)((const long long*)ei)[(long long)i + E];
            } else {
                s = ((const int*)ei)[i];
                d = ((const int*)ei)[i + E];
            }
            ss[k] = s; dd[k] = d;
            atomicAdd(&h1[d >> BIN_SHIFT], 1);
        } else {
            dd[k] = -1;
        }
    }
    __syncthreads();
    for (int i = tid; i < nbins; i += SCATTER_THREADS) {
        int c = h1[i];
        base[i] = c ? (i * BIN_CAP + atomicAdd(&gcur[i * GCUR_STRIDE], c)) : 0;
        h1[i] = 0;
    }
    __syncthreads();
#pragma unroll
    for (int k = 0; k < CHUNK_EDGES / SCATTER_THREADS; ++k) {
        if (dd[k] >= 0) {
            int bin = dd[k] >> BIN_SHIFT;
            int r = atomicAdd(&h1[bin], 1);
            int pos = base[bin] + r;
            if (pos < (bin + 1) * BIN_CAP)          // overflow guard (never expected)
                pairs[pos] = (ss[k] << BIN_SHIFT) | (dd[k] & (NODES_PER_BIN - 1));
        }
    }
}

// K2: fused degree + MFMA gemm (R11-proven).  Tile b == bin b; degree hist
// in LDS feeds the epilogue's dinv scale.  25.6 KB LDS -> 6 blocks/CU.
__global__ __launch_bounds__(256) void deg_gemm_kernel(
    const float* __restrict__ x, const float* __restrict__ W,
    const int* __restrict__ pairs, const int* __restrict__ gcur,
    unsigned short* __restrict__ h, int N) {
    __shared__ unsigned short Xs[GEMM_ROWS * 64];   // 16 KB, swizzled [row][k] bf16
    __shared__ unsigned short Ws[64 * 64];          // 8 KB,  swizzled [n][k]  bf16
    __shared__ int sdeg[NODES_PER_BIN];
    __shared__ float sdinv[NODES_PER_BIN];
    int tid = threadIdx.x;
    int b = blockIdx.x;
    int row0 = b << BIN_SHIFT;
    int nn = min(GEMM_ROWS, N - row0);
    int cntb = min(gcur[b * GCUR_STRIDE], BIN_CAP);

    if (tid < NODES_PER_BIN) sdeg[tid] = 0;
#pragma unroll
    for (int u = 0; u < 2; ++u) {
        int idx = u * 256 + tid;
        int c = idx >> 3, k0 = (idx & 7) * 8;
        float4 a = *(const float4*)&W[c * 64 + k0];
        float4 bb = *(const float4*)&W[c * 64 + k0 + 4];
        bf16x8 v;
        v[0] = (short)f2bf(a.x); v[1] = (short)f2bf(a.y);
        v[2] = (short)f2bf(a.z); v[3] = (short)f2bf(a.w);
        v[4] = (short)f2bf(bb.x); v[5] = (short)f2bf(bb.y);
        v[6] = (short)f2bf(bb.z); v[7] = (short)f2bf(bb.w);
        int byteoff = c * 128 + ((k0 * 2) ^ ((c & 7) << 4));
        *(bf16x8*)((char*)Ws + byteoff) = v;
    }
    const float* xbase = x + (size_t)row0 * DIM;
#pragma unroll
    for (int u = 0; u < 4; ++u) {
        int idx = u * 256 + tid;
        int r = idx >> 3, k0 = (idx & 7) * 8;
        float4 a = make_float4(0.f, 0.f, 0.f, 0.f), bb = a;
        if (r < nn) {
            a = *(const float4*)&xbase[r * DIM + k0];
            bb = *(const float4*)&xbase[r * DIM + k0 + 4];
        }
        bf16x8 v;
        v[0] = (short)f2bf(a.x); v[1] = (short)f2bf(a.y);
        v[2] = (short)f2bf(a.z); v[3] = (short)f2bf(a.w);
        v[4] = (short)f2bf(bb.x); v[5] = (short)f2bf(bb.y);
        v[6] = (short)f2bf(bb.z); v[7] = (short)f2bf(bb.w);
        int byteoff = r * 128 + ((k0 * 2) ^ ((r & 7) << 4));
        *(bf16x8*)((char*)Xs + byteoff) = v;
    }
    __syncthreads();                 // sdeg zeroed
    const int* pb = pairs + b * BIN_CAP;
    for (int i = tid; i < cntb; i += 256)
        atomicAdd(&sdeg[pb[i] & (NODES_PER_BIN - 1)], 1);
    __syncthreads();                 // hist done; Ws/Xs visible
    if (tid < NODES_PER_BIN)
        sdinv[tid] = rsqrtf((float)(sdeg[tid] + 1));   // +1 self-loop
    __syncthreads();                 // sdinv visible

    int w = tid >> 6, l = tid & 63;
    int lm = l & 15, kg = l >> 4;
    f32x4 acc[2][4] = {};
#pragma unroll
    for (int ks = 0; ks < 2; ++ks) {
        int kbyte = ks * 64 + kg * 16;
        int r0g = 32 * w + lm;
        int r1g = 32 * w + 16 + lm;
        bf16x8 a0 = *(const bf16x8*)((const char*)Xs + r0g * 128 + (kbyte ^ ((r0g & 7) << 4)));
        bf16x8 a1 = *(const bf16x8*)((const char*)Xs + r1g * 128 + (kbyte ^ ((r1g & 7) << 4)));
#pragma unroll
        for (int nt = 0; nt < 4; ++nt) {
            int ng = nt * 16 + lm;
            bf16x8 bv = *(const bf16x8*)((const char*)Ws + ng * 128 + (kbyte ^ ((ng & 7) << 4)));
            acc[0][nt] = __builtin_amdgcn_mfma_f32_16x16x32_bf16(a0, bv, acc[0][nt], 0, 0, 0);
            acc[1][nt] = __builtin_amdgcn_mfma_f32_16x16x32_bf16(a1, bv, acc[1][nt], 0, 0, 0);
        }
    }
#pragma unroll
    for (int mt = 0; mt < 2; ++mt) {
#pragma unroll
        for (int j = 0; j < 4; ++j) {
            int rl = 32 * w + 16 * mt + (l >> 4) * 4 + j;
            if (rl < nn) {
                float dv = sdinv[rl];
                size_t rowoff = (size_t)(row0 + rl) * DIM;
#pragma unroll
                for (int nt = 0; nt < 4; ++nt)
                    h[rowoff + nt * 16 + lm] = f2bf(acc[mt][nt][j] * dv);
            }
        }
    }
}

// K3: sorted aggregate — ZERO atomics in the accumulate phase.
// Phase 1: counting-sort the bin's pairs by dst-local in LDS (hist -> scan
// -> rank-scatter) giving contiguous per-node src runs.  Phase 2: 16-lane
// group walks its 4 nodes' runs, fp32 register accumulation, deg/dinv from
// run length, direct out write.  9.7 KB LDS, 512 threads, 4 blocks/CU.
__global__ __launch_bounds__(512) void aggregate_kernel(
    const unsigned short* __restrict__ h, const int* __restrict__ pairs,
    const int* __restrict__ gcur, const float* __restrict__ bias,
    float* __restrict__ out, int N) {
    __shared__ int rp[NODES_PER_BIN + 1];   // rowptr (exclusive prefix)
    __shared__ int cur[NODES_PER_BIN];      // rank cursors
    __shared__ int ssrc[BIN_CAP];           // dst-sorted src ids (8 KB)
    int b = blockIdx.x;
    int tid = threadIdx.x;
    int cnt = min(gcur[b * GCUR_STRIDE], BIN_CAP);
    int node0 = b << BIN_SHIFT;
    int nn = min(NODES_PER_BIN, N - node0);

    if (tid < NODES_PER_BIN) cur[tid] = 0;      // reuse as histogram first
    __syncthreads();
    const int* pb = pairs + b * BIN_CAP;
    int pk[4]; int np = 0;
    for (int i = tid; i < cnt; i += 512) {
        int p = pb[i];
        pk[np++] = p;
        atomicAdd(&cur[p & (NODES_PER_BIN - 1)], 1);
    }
    __syncthreads();
    if (tid < NODES_PER_BIN) rp[tid + 1] = cur[tid];
    if (tid == 0) rp[0] = 0;
    __syncthreads();
    // Hillis-Steele inclusive scan over rp[1..128]
#pragma unroll
    for (int s = 1; s < NODES_PER_BIN; s <<= 1) {
        int v = 0;
        if (tid < NODES_PER_BIN && tid >= s) v = rp[tid + 1 - s];
        __syncthreads();
        if (tid < NODES_PER_BIN && tid >= s) rp[tid + 1] += v;
        __syncthreads();
    }
    if (tid < NODES_PER_BIN) cur[tid] = rp[tid];
    __syncthreads();
#pragma unroll 4
    for (int k = 0; k < np; ++k) {
        int r = atomicAdd(&cur[pk[k] & (NODES_PER_BIN - 1)], 1);
        ssrc[r] = pk[k] >> BIN_SHIFT;
    }
    __syncthreads();

    // walk phase: group = 16 lanes (4 features/lane), 32 groups x 4 nodes
    int grp = tid >> 4, fl = tid & 15;
    float4 bl = *(const float4*)&bias[4 * fl];
#pragma unroll 1
    for (int k = 0; k < 4; ++k) {
        int n = 4 * grp + k;
        if (n >= nn) continue;                  // no barriers below: safe
        int s = rp[n], e = rp[n + 1];
        float a0 = 0.f, a1 = 0.f, a2 = 0.f, a3 = 0.f;
        int j = s;
        for (; j + 4 <= e; j += 4) {            // 4 gathers in flight
            int s0 = ssrc[j], s1 = ssrc[j + 1], s2 = ssrc[j + 2], s3 = ssrc[j + 3];
            ushort4 r0 = *(const ushort4*)(h + (size_t)s0 * DIM + 4 * fl);
            ushort4 r1 = *(const ushort4*)(h + (size_t)s1 * DIM + 4 * fl);
            ushort4 r2 = *(const ushort4*)(h + (size_t)s2 * DIM + 4 * fl);
            ushort4 r3 = *(const ushort4*)(h + (size_t)s3 * DIM + 4 * fl);
            a0 += (bf2f(r0.x) + bf2f(r1.x)) + (bf2f(r2.x) + bf2f(r3.x));
            a1 += (bf2f(r0.y) + bf2f(r1.y)) + (bf2f(r2.y) + bf2f(r3.y));
            a2 += (bf2f(r0.z) + bf2f(r1.z)) + (bf2f(r2.z) + bf2f(r3.z));
            a3 += (bf2f(r0.w) + bf2f(r1.w)) + (bf2f(r2.w) + bf2f(r3.w));
        }
        for (; j < e; ++j) {
            int s0 = ssrc[j];
            ushort4 r0 = *(const ushort4*)(h + (size_t)s0 * DIM + 4 * fl);
            a0 += bf2f(r0.x); a1 += bf2f(r0.y);
            a2 += bf2f(r0.z); a3 += bf2f(r0.w);
        }
        int gn = node0 + n;
        ushort4 sh = *(const ushort4*)(h + (size_t)gn * DIM + 4 * fl);  // self (pre-scaled)
        float di = rsqrtf((float)(e - s + 1));                          // dinv[dst], local
        float4 o;
        o.x = (a0 + bf2f(sh.x)) * di + bl.x;
        o.y = (a1 + bf2f(sh.y)) * di + bl.y;
        o.z = (a2 + bf2f(sh.z)) * di + bl.z;
        o.w = (a3 + bf2f(sh.w)) * di + bl.w;
        *(float4*)&out[(size_t)gn * DIM + 4 * fl] = o;
    }
}

extern "C" void kernel_launch(void* const* d_in, const int* in_sizes, int n_in,
                              void* d_out, int out_size, void* d_ws, size_t ws_size,
                              hipStream_t stream) {
    const float* x = (const float*)d_in[0];
    const void* ei = d_in[1];
    const float* W = (const float*)d_in[2];
    const float* b = (const float*)d_in[3];
    float* out = (float*)d_out;

    int N = in_sizes[0] / DIM;   // 100000
    int E = in_sizes[1] / 2;     // 1000000
    int nbins = (N + NODES_PER_BIN - 1) >> BIN_SHIFT;   // 782

    char* ws = (char*)d_ws;
    auto align256 = [](size_t v) { return (v + 255) & ~(size_t)255; };
    size_t off = 0;
    int* gcur = (int*)(ws + off);              off = align256(off + (size_t)MAX_BINS * GCUR_STRIDE * 4);
    int* pairs = (int*)(ws + off);             off = align256(off + ((size_t)nbins * BIN_CAP + 64) * 4);
    unsigned short* h = (unsigned short*)(ws + off); off = align256(off + (size_t)(N + 1) * DIM * 2);

    int nchunks = (E + CHUNK_EDGES - 1) / CHUNK_EDGES;       // 245

    hipMemsetAsync(gcur, 0, (size_t)MAX_BINS * GCUR_STRIDE * 4, stream);
    bin_scatter_kernel<<<nchunks, SCATTER_THREADS, 0, stream>>>(ei, gcur, pairs, E, nbins);
    deg_gemm_kernel<<<nbins, 256, 0, stream>>>(x, W, pairs, gcur, h, N);
    aggregate_kernel<<<nbins, 512, 0, stream>>>(h, pairs, gcur, b, out, N);
}

// Round 13
// 127.124 us; speedup vs baseline: 1.0693x; 1.0693x over previous
//
#include <hip/hip_runtime.h>

#define DIM 64
#define BIN_SHIFT 7                  // 128 nodes per bin
#define NODES_PER_BIN 128
#define MAX_BINS 1024                // ceil(100000/128)=782 <= 1024
#define BIN_CAP 2048                 // mean 1279, sigma ~36 -> 21-sigma margin
#define CHUNK_EDGES 4096             // edges per scatter block (R11-proven)
#define SCATTER_THREADS 1024         // 4 edges/thread (R11-proven)
#define GEMM_ROWS 128                // rows per gemm block == nodes per bin
#define FXSCALE 65536.0f             // fixed-point scale 2^16
#define FXINV (1.0f / 65536.0f)
#define FXBIAS 524288u               // 2^19 per-term bias (|v|<8 -> term >= 0)
#define MAGIC 12582912.0f            // 1.5*2^23 RNE float->int magic
#define MAGIC_I 0x4B400000u
#define ACC_U64 33                   // u64 per node row: 32 used + 1 pad

// ws layout (256-aligned):
// gcur[MAX_BINS] | deg[N+1] | dinv[N+1] | pairs[nbins*BIN_CAP+64] | h[(N+1)*64] bf16
//
// Pipeline (1 memset + 3 dispatches) — R11 structure (best measured, 128.6us):
//   memset gcur
//   K1 scatter: bin scatter, 1024 thr x 4096 edges
//   K2 deg_gemm: bin-degree hist in LDS -> sdinv -> MFMA gemm; writes deg/dinv
//   K3 aggregate: one block/bin, u64-packed biased fixed-point LDS atomics;
//                 R13 change: ushort8 gathers, 8 lanes/edge -> 64 edges in
//                 flight per wave (2x MLP, same traffic, same atomic count)

using bf16x8 = __attribute__((ext_vector_type(8))) short;
using u16x8  = __attribute__((ext_vector_type(8))) unsigned short;
using f32x4  = __attribute__((ext_vector_type(4))) float;

__device__ __forceinline__ unsigned short f2bf(float f) {
    unsigned u = __float_as_uint(f);
    u += 0x7fffu + ((u >> 16) & 1u);     // round-to-nearest-even
    return (unsigned short)(u >> 16);
}
__device__ __forceinline__ float bf2f(unsigned short u) {
    return __uint_as_float((unsigned)u << 16);
}
__device__ __forceinline__ unsigned fxq(unsigned short bf) {   // bf16 -> biased fx
    return __float_as_uint(fmaf(bf2f(bf), FXSCALE, MAGIC)) - (MAGIC_I - FXBIAS);
}

// K1: scatter packed (src<<7 | dst&127) into dst-bins.  1024 threads, 4
// edges/thread.  One reservation atomic per (block,bin); contiguous runs.
__global__ __launch_bounds__(SCATTER_THREADS) void bin_scatter_kernel(
    const void* __restrict__ ei, int* __restrict__ gcur,
    int* __restrict__ pairs, int E, int nbins) {
    __shared__ int h1[MAX_BINS];
    __shared__ int base[MAX_BINS];
    __shared__ int s_notz;
    int tid = threadIdx.x;
    if (tid == 0) s_notz = 0;
    for (int i = tid; i < nbins; i += SCATTER_THREADS) h1[i] = 0;
    __syncthreads();
    if (((const int*)ei)[2 * tid + 1] != 0) s_notz = 1;   // benign race (same value)
    __syncthreads();
    int is64 = (s_notz == 0);
    int chunk = blockIdx.x * CHUNK_EDGES;

    int ss[CHUNK_EDGES / SCATTER_THREADS], dd[CHUNK_EDGES / SCATTER_THREADS];
#pragma unroll
    for (int k = 0; k < CHUNK_EDGES / SCATTER_THREADS; ++k) {
        int i = chunk + k * SCATTER_THREADS + tid;
        if (i < E) {
            int s, d;
            if (is64) {
                s = (int)((const long long*)ei)[i];
                d = (int)((const long long*)ei)[(long long)i + E];
            } else {
                s = ((const int*)ei)[i];
                d = ((const int*)ei)[i + E];
            }
            ss[k] = s; dd[k] = d;
            atomicAdd(&h1[d >> BIN_SHIFT], 1);
        } else {
            dd[k] = -1;
        }
    }
    __syncthreads();
    for (int i = tid; i < nbins; i += SCATTER_THREADS) {
        int c = h1[i];
        base[i] = c ? (i * BIN_CAP + atomicAdd(&gcur[i], c)) : 0;
        h1[i] = 0;
    }
    __syncthreads();
#pragma unroll
    for (int k = 0; k < CHUNK_EDGES / SCATTER_THREADS; ++k) {
        if (dd[k] >= 0) {
            int bin = dd[k] >> BIN_SHIFT;
            int r = atomicAdd(&h1[bin], 1);
            int pos = base[bin] + r;
            if (pos < (bin + 1) * BIN_CAP)          // overflow guard (never expected)
                pairs[pos] = (ss[k] << BIN_SHIFT) | (dd[k] & (NODES_PER_BIN - 1));
        }
    }
}

// K2: fused degree + MFMA gemm (R11-proven).  Tile b == bin b; degree hist
// in LDS feeds the epilogue's dinv scale; deg/dinv written for K3.
__global__ __launch_bounds__(256) void deg_gemm_kernel(
    const float* __restrict__ x, const float* __restrict__ W,
    const int* __restrict__ pairs, const int* __restrict__ gcur,
    int* __restrict__ deg, float* __restrict__ dinv,
    unsigned short* __restrict__ h, int N) {
    __shared__ unsigned short Xs[GEMM_ROWS * 64];   // 16 KB, swizzled [row][k] bf16
    __shared__ unsigned short Ws[64 * 64];          // 8 KB,  swizzled [n][k]  bf16
    __shared__ int sdeg[NODES_PER_BIN];
    __shared__ float sdinv[NODES_PER_BIN];
    int tid = threadIdx.x;
    int b = blockIdx.x;
    int row0 = b << BIN_SHIFT;
    int nn = min(GEMM_ROWS, N - row0);
    int cntb = min(gcur[b], BIN_CAP);

    if (tid < NODES_PER_BIN) sdeg[tid] = 0;
#pragma unroll
    for (int u = 0; u < 2; ++u) {
        int idx = u * 256 + tid;
        int c = idx >> 3, k0 = (idx & 7) * 8;
        float4 a = *(const float4*)&W[c * 64 + k0];
        float4 bb = *(const float4*)&W[c * 64 + k0 + 4];
        bf16x8 v;
        v[0] = (short)f2bf(a.x); v[1] = (short)f2bf(a.y);
        v[2] = (short)f2bf(a.z); v[3] = (short)f2bf(a.w);
        v[4] = (short)f2bf(bb.x); v[5] = (short)f2bf(bb.y);
        v[6] = (short)f2bf(bb.z); v[7] = (short)f2bf(bb.w);
        int byteoff = c * 128 + ((k0 * 2) ^ ((c & 7) << 4));
        *(bf16x8*)((char*)Ws + byteoff) = v;
    }
    const float* xbase = x + (size_t)row0 * DIM;
#pragma unroll
    for (int u = 0; u < 4; ++u) {
        int idx = u * 256 + tid;
        int r = idx >> 3, k0 = (idx & 7) * 8;
        float4 a = make_float4(0.f, 0.f, 0.f, 0.f), bb = a;
        if (r < nn) {
            a = *(const float4*)&xbase[r * DIM + k0];
            bb = *(const float4*)&xbase[r * DIM + k0 + 4];
        }
        bf16x8 v;
        v[0] = (short)f2bf(a.x); v[1] = (short)f2bf(a.y);
        v[2] = (short)f2bf(a.z); v[3] = (short)f2bf(a.w);
        v[4] = (short)f2bf(bb.x); v[5] = (short)f2bf(bb.y);
        v[6] = (short)f2bf(bb.z); v[7] = (short)f2bf(bb.w);
        int byteoff = r * 128 + ((k0 * 2) ^ ((r & 7) << 4));
        *(bf16x8*)((char*)Xs + byteoff) = v;
    }
    __syncthreads();                 // sdeg zeroed
    const int* pb = pairs + b * BIN_CAP;
    for (int i = tid; i < cntb; i += 256)
        atomicAdd(&sdeg[pb[i] & (NODES_PER_BIN - 1)], 1);
    __syncthreads();                 // hist done; Ws/Xs visible
    if (tid < NODES_PER_BIN) {
        int d = sdeg[tid];
        float dv = rsqrtf((float)(d + 1));     // +1 self-loop
        sdinv[tid] = dv;
        if (tid < nn) {
            deg[row0 + tid] = d;
            dinv[row0 + tid] = dv;
        }
    }
    __syncthreads();                 // sdinv visible

    int w = tid >> 6, l = tid & 63;
    int lm = l & 15, kg = l >> 4;
    f32x4 acc[2][4] = {};
#pragma unroll
    for (int ks = 0; ks < 2; ++ks) {
        int kbyte = ks * 64 + kg * 16;
        int r0g = 32 * w + lm;
        int r1g = 32 * w + 16 + lm;
        bf16x8 a0 = *(const bf16x8*)((const char*)Xs + r0g * 128 + (kbyte ^ ((r0g & 7) << 4)));
        bf16x8 a1 = *(const bf16x8*)((const char*)Xs + r1g * 128 + (kbyte ^ ((r1g & 7) << 4)));
#pragma unroll
        for (int nt = 0; nt < 4; ++nt) {
            int ng = nt * 16 + lm;
            bf16x8 bv = *(const bf16x8*)((const char*)Ws + ng * 128 + (kbyte ^ ((ng & 7) << 4)));
            acc[0][nt] = __builtin_amdgcn_mfma_f32_16x16x32_bf16(a0, bv, acc[0][nt], 0, 0, 0);
            acc[1][nt] = __builtin_amdgcn_mfma_f32_16x16x32_bf16(a1, bv, acc[1][nt], 0, 0, 0);
        }
    }
#pragma unroll
    for (int mt = 0; mt < 2; ++mt) {
#pragma unroll
        for (int j = 0; j < 4; ++j) {
            int rl = 32 * w + 16 * mt + (l >> 4) * 4 + j;
            if (rl < nn) {
                float dv = sdinv[rl];
                size_t rowoff = (size_t)(row0 + rl) * DIM;
#pragma unroll
                for (int nt = 0; nt < 4; ++nt)
                    h[rowoff + nt * 16 + lm] = f2bf(acc[mt][nt][j] * dv);
            }
        }
    }
}

// K3: full-feature aggregate, one block per bin (no fetch amplification).
// 512 threads = 8 waves; lane group = 8 lanes/edge x ushort8 (16 B) ->
// 64 edges in flight per wave-iter (2x R11's MLP, identical traffic and
// 0.5 LDS-atomic wave-instr/edge).  33 KB LDS -> 4 blocks/CU.
__global__ __launch_bounds__(512) void aggregate_kernel(
    const unsigned short* __restrict__ h, const int* __restrict__ pairs,
    const int* __restrict__ gcur, const int* __restrict__ deg,
    const float* __restrict__ dinv, const float* __restrict__ bias,
    float* __restrict__ out, int N) {
    __shared__ unsigned long long acc[NODES_PER_BIN * ACC_U64];   // 33792 B
    int b = blockIdx.x;
    int tid = threadIdx.x;
    int cnt = min(gcur[b], BIN_CAP);
    int node0 = b << BIN_SHIFT;
    int nn = min(NODES_PER_BIN, N - node0);

    for (int i = tid; i < NODES_PER_BIN * ACC_U64; i += 512) acc[i] = 0ULL;
    __syncthreads();

    int wave = tid >> 6, lane = tid & 63;
    int g = lane >> 3;                 // edge slot 0..7
    int fq = lane & 7;                 // features 8*fq .. 8*fq+7
    const int* pb = pairs + b * BIN_CAP;
    int dummy = N << BIN_SHIFT;        // row N load is garbage but gated off

    for (int j0 = 64 * wave; j0 < cnt; j0 += 512) {
        int pk[8]; bool vd[8];
#pragma unroll
        for (int u = 0; u < 8; ++u) {
            int e = j0 + 8 * u + g;
            vd[u] = (e < cnt);
            pk[u] = vd[u] ? pb[e] : dummy;
        }
        u16x8 r[8];
#pragma unroll
        for (int u = 0; u < 8; ++u)    // issue all 8 x 16B gathers before use
            r[u] = *(const u16x8*)(h + (size_t)(pk[u] >> BIN_SHIFT) * DIM + 8 * fq);
#pragma unroll
        for (int u = 0; u < 8; ++u) {
            unsigned q0 = fxq(r[u][0]), q1 = fxq(r[u][1]);
            unsigned q2 = fxq(r[u][2]), q3 = fxq(r[u][3]);
            unsigned q4 = fxq(r[u][4]), q5 = fxq(r[u][5]);
            unsigned q6 = fxq(r[u][6]), q7 = fxq(r[u][7]);
            if (vd[u]) {
                unsigned long long* ar =
                    &acc[(pk[u] & (NODES_PER_BIN - 1)) * ACC_U64 + 4 * fq];
                atomicAdd(&ar[0], (unsigned long long)q0 | ((unsigned long long)q1 << 32));
                atomicAdd(&ar[1], (unsigned long long)q2 | ((unsigned long long)q3 << 32));
                atomicAdd(&ar[2], (unsigned long long)q4 | ((unsigned long long)q5 << 32));
                atomicAdd(&ar[3], (unsigned long long)q6 | ((unsigned long long)q7 << 32));
            }
        }
    }
    __syncthreads();

    // dword view: feature f (0..63) of node n at dword [n*66 + f]
    const int* accd = (const int*)acc;
    float bl = bias[lane];
    for (int n0 = wave; n0 < nn; n0 += 8) {
        int gn = node0 + n0;
        int dgn = deg[gn];
        float di = dinv[gn];
        unsigned q = (unsigned)accd[n0 * (2 * ACC_U64) + lane];
        int sfx = (int)(q - (unsigned)dgn * FXBIAS);        // remove per-term bias
        float sum = (float)sfx * FXINV;
        float self = bf2f(h[(size_t)gn * DIM + lane]);      // pre-scaled by dinv[gn]
        out[(size_t)gn * DIM + lane] = (sum + self) * di + bl;
    }
}

extern "C" void kernel_launch(void* const* d_in, const int* in_sizes, int n_in,
                              void* d_out, int out_size, void* d_ws, size_t ws_size,
                              hipStream_t stream) {
    const float* x = (const float*)d_in[0];
    const void* ei = d_in[1];
    const float* W = (const float*)d_in[2];
    const float* b = (const float*)d_in[3];
    float* out = (float*)d_out;

    int N = in_sizes[0] / DIM;   // 100000
    int E = in_sizes[1] / 2;     // 1000000
    int nbins = (N + NODES_PER_BIN - 1) >> BIN_SHIFT;   // 782

    char* ws = (char*)d_ws;
    auto align256 = [](size_t v) { return (v + 255) & ~(size_t)255; };
    size_t off = 0;
    int* gcur = (int*)(ws + off);              off = align256(off + (size_t)MAX_BINS * 4);
    int* deg  = (int*)(ws + off);              off = align256(off + (size_t)(N + 1) * 4);
    float* dinv = (float*)(ws + off);          off = align256(off + (size_t)(N + 1) * 4);
    int* pairs = (int*)(ws + off);             off = align256(off + ((size_t)nbins * BIN_CAP + 64) * 4);
    unsigned short* h = (unsigned short*)(ws + off); off = align256(off + (size_t)(N + 1) * DIM * 2);

    int nchunks = (E + CHUNK_EDGES - 1) / CHUNK_EDGES;       // 245

    hipMemsetAsync(gcur, 0, (size_t)MAX_BINS * 4, stream);
    bin_scatter_kernel<<<nchunks, SCATTER_THREADS, 0, stream>>>(ei, gcur, pairs, E, nbins);
    deg_gemm_kernel<<<nbins, 256, 0, stream>>>(x, W, pairs, gcur, deg, dinv, h, N);
    aggregate_kernel<<<nbins, 512, 0, stream>>>(h, pairs, gcur, deg, dinv, b, out, N);
}

// Round 14
// 126.627 us; speedup vs baseline: 1.0735x; 1.0039x over previous
//
#include <hip/hip_runtime.h>

#define DIM 64
#define BIN_SHIFT 7                  // 128 nodes per bin
#define NODES_PER_BIN 128
#define MAX_BINS 1024                // ceil(100000/128)=782 <= 1024
#define BIN_CAP 2048                 // mean 1279, sigma ~36 -> 21-sigma margin
#define CHUNK_EDGES 4096             // edges per scatter block (R11-proven)
#define SCATTER_THREADS 1024         // 4 edges/thread (R11-proven)
#define GEMM_ROWS 128                // rows per gemm block == nodes per bin
#define FXSCALE 65536.0f             // fixed-point scale 2^16
#define FXINV (1.0f / 65536.0f)
#define FXBIAS 524288u               // 2^19 per-term bias (|v|<8 -> term >= 0)
#define MAGIC 12582912.0f            // 1.5*2^23 RNE float->int magic
#define MAGIC_I 0x4B400000u
#define ACC_U64 33                   // u64 per node row: 32 used + 1 pad

// ws layout (256-aligned):
// gcur[MAX_BINS] | deg[N+1] | dinv[N+1] | pairs[nbins*BIN_CAP+64] | h[(N+1)*64] bf16
//
// Pipeline (1 memset + 3 dispatches) — R13 structure (best measured, 127.1us):
//   memset gcur
//   K1 scatter: R14 change — reservation-return latency hidden under the
//               per-edge rank loop (separate h2 rank array; return consumed
//               AFTER the rank loop, single barrier before the write phase)
//   K2 deg_gemm: bin-degree hist in LDS -> sdinv -> MFMA gemm; writes deg/dinv
//   K3 aggregate: one block/bin, ushort8 gathers, u64-packed fx LDS atomics

using bf16x8 = __attribute__((ext_vector_type(8))) short;
using u16x8  = __attribute__((ext_vector_type(8))) unsigned short;
using f32x4  = __attribute__((ext_vector_type(4))) float;

__device__ __forceinline__ unsigned short f2bf(float f) {
    unsigned u = __float_as_uint(f);
    u += 0x7fffu + ((u >> 16) & 1u);     // round-to-nearest-even
    return (unsigned short)(u >> 16);
}
__device__ __forceinline__ float bf2f(unsigned short u) {
    return __uint_as_float((unsigned)u << 16);
}
__device__ __forceinline__ unsigned fxq(unsigned short bf) {   // bf16 -> biased fx
    return __float_as_uint(fmaf(bf2f(bf), FXSCALE, MAGIC)) - (MAGIC_I - FXBIAS);
}

// K1: scatter packed (src<<7 | dst&127) into dst-bins.  1024 threads, 4
// edges/thread.  Reservation-return overlap: issue gcur atomic, rank edges
// into h2 while the return is in flight, consume return after.
__global__ __launch_bounds__(SCATTER_THREADS) void bin_scatter_kernel(
    const void* __restrict__ ei, int* __restrict__ gcur,
    int* __restrict__ pairs, int E, int nbins) {
    __shared__ int h1[MAX_BINS];     // phase-1 histogram (counts)
    __shared__ int h2[MAX_BINS];     // phase-2b rank counters (disjoint from h1)
    __shared__ int base[MAX_BINS];
    __shared__ int s_notz;
    int tid = threadIdx.x;
    if (tid == 0) s_notz = 0;
    for (int i = tid; i < nbins; i += SCATTER_THREADS) { h1[i] = 0; h2[i] = 0; }
    __syncthreads();
    if (((const int*)ei)[2 * tid + 1] != 0) s_notz = 1;   // benign race (same value)
    __syncthreads();
    int is64 = (s_notz == 0);
    int chunk = blockIdx.x * CHUNK_EDGES;

    int ss[CHUNK_EDGES / SCATTER_THREADS], dd[CHUNK_EDGES / SCATTER_THREADS];
#pragma unroll
    for (int k = 0; k < CHUNK_EDGES / SCATTER_THREADS; ++k) {
        int i = chunk + k * SCATTER_THREADS + tid;
        if (i < E) {
            int s, d;
            if (is64) {
                s = (int)((const long long*)ei)[i];
                d = (int)((const long long*)ei)[(long long)i + E];
            } else {
                s = ((const int*)ei)[i];
                d = ((const int*)ei)[i + E];
            }
            ss[k] = s; dd[k] = d;
            atomicAdd(&h1[d >> BIN_SHIFT], 1);
        } else {
            dd[k] = -1;
        }
    }
    __syncthreads();                       // h1 counts final

    // Phase 2a: ISSUE reservation (return not consumed yet).  tid<nbins: one
    // bin per thread (nbins=782 <= 1024 threads).
    int myc = 0, ret = 0;
    if (tid < nbins) {
        myc = h1[tid];
        if (myc) ret = atomicAdd(&gcur[tid], myc);   // in flight during 2b
    }
    // Phase 2b: per-edge ranks into h2 — independent of the returns.
    int rk[CHUNK_EDGES / SCATTER_THREADS];
#pragma unroll
    for (int k = 0; k < CHUNK_EDGES / SCATTER_THREADS; ++k)
        if (dd[k] >= 0) rk[k] = atomicAdd(&h2[dd[k] >> BIN_SHIFT], 1);
    // Consume return (waitcnt lands here, after ~2-4us of LDS rank work).
    if (myc) base[tid] = tid * BIN_CAP + ret;
    __syncthreads();                       // base + ranks visible

#pragma unroll
    for (int k = 0; k < CHUNK_EDGES / SCATTER_THREADS; ++k) {
        if (dd[k] >= 0) {
            int bin = dd[k] >> BIN_SHIFT;
            int pos = base[bin] + rk[k];
            if (pos < (bin + 1) * BIN_CAP)          // overflow guard (never expected)
                pairs[pos] = (ss[k] << BIN_SHIFT) | (dd[k] & (NODES_PER_BIN - 1));
        }
    }
}

// K2: fused degree + MFMA gemm (R11-proven).  Tile b == bin b; degree hist
// in LDS feeds the epilogue's dinv scale; deg/dinv written for K3.
__global__ __launch_bounds__(256) void deg_gemm_kernel(
    const float* __restrict__ x, const float* __restrict__ W,
    const int* __restrict__ pairs, const int* __restrict__ gcur,
    int* __restrict__ deg, float* __restrict__ dinv,
    unsigned short* __restrict__ h, int N) {
    __shared__ unsigned short Xs[GEMM_ROWS * 64];   // 16 KB, swizzled [row][k] bf16
    __shared__ unsigned short Ws[64 * 64];          // 8 KB,  swizzled [n][k]  bf16
    __shared__ int sdeg[NODES_PER_BIN];
    __shared__ float sdinv[NODES_PER_BIN];
    int tid = threadIdx.x;
    int b = blockIdx.x;
    int row0 = b << BIN_SHIFT;
    int nn = min(GEMM_ROWS, N - row0);
    int cntb = min(gcur[b], BIN_CAP);

    if (tid < NODES_PER_BIN) sdeg[tid] = 0;
#pragma unroll
    for (int u = 0; u < 2; ++u) {
        int idx = u * 256 + tid;
        int c = idx >> 3, k0 = (idx & 7) * 8;
        float4 a = *(const float4*)&W[c * 64 + k0];
        float4 bb = *(const float4*)&W[c * 64 + k0 + 4];
        bf16x8 v;
        v[0] = (short)f2bf(a.x); v[1] = (short)f2bf(a.y);
        v[2] = (short)f2bf(a.z); v[3] = (short)f2bf(a.w);
        v[4] = (short)f2bf(bb.x); v[5] = (short)f2bf(bb.y);
        v[6] = (short)f2bf(bb.z); v[7] = (short)f2bf(bb.w);
        int byteoff = c * 128 + ((k0 * 2) ^ ((c & 7) << 4));
        *(bf16x8*)((char*)Ws + byteoff) = v;
    }
    const float* xbase = x + (size_t)row0 * DIM;
#pragma unroll
    for (int u = 0; u < 4; ++u) {
        int idx = u * 256 + tid;
        int r = idx >> 3, k0 = (idx & 7) * 8;
        float4 a = make_float4(0.f, 0.f, 0.f, 0.f), bb = a;
        if (r < nn) {
            a = *(const float4*)&xbase[r * DIM + k0];
            bb = *(const float4*)&xbase[r * DIM + k0 + 4];
        }
        bf16x8 v;
        v[0] = (short)f2bf(a.x); v[1] = (short)f2bf(a.y);
        v[2] = (short)f2bf(a.z); v[3] = (short)f2bf(a.w);
        v[4] = (short)f2bf(bb.x); v[5] = (short)f2bf(bb.y);
        v[6] = (short)f2bf(bb.z); v[7] = (short)f2bf(bb.w);
        int byteoff = r * 128 + ((k0 * 2) ^ ((r & 7) << 4));
        *(bf16x8*)((char*)Xs + byteoff) = v;
    }
    __syncthreads();                 // sdeg zeroed
    const int* pb = pairs + b * BIN_CAP;
    for (int i = tid; i < cntb; i += 256)
        atomicAdd(&sdeg[pb[i] & (NODES_PER_BIN - 1)], 1);
    __syncthreads();                 // hist done; Ws/Xs visible
    if (tid < NODES_PER_BIN) {
        int d = sdeg[tid];
        float dv = rsqrtf((float)(d + 1));     // +1 self-loop
        sdinv[tid] = dv;
        if (tid < nn) {
            deg[row0 + tid] = d;
            dinv[row0 + tid] = dv;
        }
    }
    __syncthreads();                 // sdinv visible

    int w = tid >> 6, l = tid & 63;
    int lm = l & 15, kg = l >> 4;
    f32x4 acc[2][4] = {};
#pragma unroll
    for (int ks = 0; ks < 2; ++ks) {
        int kbyte = ks * 64 + kg * 16;
        int r0g = 32 * w + lm;
        int r1g = 32 * w + 16 + lm;
        bf16x8 a0 = *(const bf16x8*)((const char*)Xs + r0g * 128 + (kbyte ^ ((r0g & 7) << 4)));
        bf16x8 a1 = *(const bf16x8*)((const char*)Xs + r1g * 128 + (kbyte ^ ((r1g & 7) << 4)));
#pragma unroll
        for (int nt = 0; nt < 4; ++nt) {
            int ng = nt * 16 + lm;
            bf16x8 bv = *(const bf16x8*)((const char*)Ws + ng * 128 + (kbyte ^ ((ng & 7) << 4)));
            acc[0][nt] = __builtin_amdgcn_mfma_f32_16x16x32_bf16(a0, bv, acc[0][nt], 0, 0, 0);
            acc[1][nt] = __builtin_amdgcn_mfma_f32_16x16x32_bf16(a1, bv, acc[1][nt], 0, 0, 0);
        }
    }
#pragma unroll
    for (int mt = 0; mt < 2; ++mt) {
#pragma unroll
        for (int j = 0; j < 4; ++j) {
            int rl = 32 * w + 16 * mt + (l >> 4) * 4 + j;
            if (rl < nn) {
                float dv = sdinv[rl];
                size_t rowoff = (size_t)(row0 + rl) * DIM;
#pragma unroll
                for (int nt = 0; nt < 4; ++nt)
                    h[rowoff + nt * 16 + lm] = f2bf(acc[mt][nt][j] * dv);
            }
        }
    }
}

// K3: full-feature aggregate, one block per bin (no fetch amplification).
// 512 threads = 8 waves; 8 lanes/edge x ushort8 -> 64 edges in flight per
// wave-iter; 4 u64 LDS atomics per edge over 8 lanes (0.5 wave-instr/edge).
// 33 KB LDS -> 4 blocks/CU.
__global__ __launch_bounds__(512) void aggregate_kernel(
    const unsigned short* __restrict__ h, const int* __restrict__ pairs,
    const int* __restrict__ gcur, const int* __restrict__ deg,
    const float* __restrict__ dinv, const float* __restrict__ bias,
    float* __restrict__ out, int N) {
    __shared__ unsigned long long acc[NODES_PER_BIN * ACC_U64];   // 33792 B
    int b = blockIdx.x;
    int tid = threadIdx.x;
    int cnt = min(gcur[b], BIN_CAP);
    int node0 = b << BIN_SHIFT;
    int nn = min(NODES_PER_BIN, N - node0);

    for (int i = tid; i < NODES_PER_BIN * ACC_U64; i += 512) acc[i] = 0ULL;
    __syncthreads();

    int wave = tid >> 6, lane = tid & 63;
    int g = lane >> 3;                 // edge slot 0..7
    int fq = lane & 7;                 // features 8*fq .. 8*fq+7
    const int* pb = pairs + b * BIN_CAP;
    int dummy = N << BIN_SHIFT;        // row N load is garbage but gated off

    for (int j0 = 64 * wave; j0 < cnt; j0 += 512) {
        int pk[8]; bool vd[8];
#pragma unroll
        for (int u = 0; u < 8; ++u) {
            int e = j0 + 8 * u + g;
            vd[u] = (e < cnt);
            pk[u] = vd[u] ? pb[e] : dummy;
        }
        u16x8 r[8];
#pragma unroll
        for (int u = 0; u < 8; ++u)    // issue all 8 x 16B gathers before use
            r[u] = *(const u16x8*)(h + (size_t)(pk[u] >> BIN_SHIFT) * DIM + 8 * fq);
#pragma unroll
        for (int u = 0; u < 8; ++u) {
            unsigned q0 = fxq(r[u][0]), q1 = fxq(r[u][1]);
            unsigned q2 = fxq(r[u][2]), q3 = fxq(r[u][3]);
            unsigned q4 = fxq(r[u][4]), q5 = fxq(r[u][5]);
            unsigned q6 = fxq(r[u][6]), q7 = fxq(r[u][7]);
            if (vd[u]) {
                unsigned long long* ar =
                    &acc[(pk[u] & (NODES_PER_BIN - 1)) * ACC_U64 + 4 * fq];
                atomicAdd(&ar[0], (unsigned long long)q0 | ((unsigned long long)q1 << 32));
                atomicAdd(&ar[1], (unsigned long long)q2 | ((unsigned long long)q3 << 32));
                atomicAdd(&ar[2], (unsigned long long)q4 | ((unsigned long long)q5 << 32));
                atomicAdd(&ar[3], (unsigned long long)q6 | ((unsigned long long)q7 << 32));
            }
        }
    }
    __syncthreads();

    // dword view: feature f (0..63) of node n at dword [n*66 + f]
    const int* accd = (const int*)acc;
    float bl = bias[lane];
    for (int n0 = wave; n0 < nn; n0 += 8) {
        int gn = node0 + n0;
        int dgn = deg[gn];
        float di = dinv[gn];
        unsigned q = (unsigned)accd[n0 * (2 * ACC_U64) + lane];
        int sfx = (int)(q - (unsigned)dgn * FXBIAS);        // remove per-term bias
        float sum = (float)sfx * FXINV;
        float self = bf2f(h[(size_t)gn * DIM + lane]);      // pre-scaled by dinv[gn]
        out[(size_t)gn * DIM + lane] = (sum + self) * di + bl;
    }
}

extern "C" void kernel_launch(void* const* d_in, const int* in_sizes, int n_in,
                              void* d_out, int out_size, void* d_ws, size_t ws_size,
                              hipStream_t stream) {
    const float* x = (const float*)d_in[0];
    const void* ei = d_in[1];
    const float* W = (const float*)d_in[2];
    const float* b = (const float*)d_in[3];
    float* out = (float*)d_out;

    int N = in_sizes[0] / DIM;   // 100000
    int E = in_sizes[1] / 2;     // 1000000
    int nbins = (N + NODES_PER_BIN - 1) >> BIN_SHIFT;   // 782

    char* ws = (char*)d_ws;
    auto align256 = [](size_t v) { return (v + 255) & ~(size_t)255; };
    size_t off = 0;
    int* gcur = (int*)(ws + off);              off = align256(off + (size_t)MAX_BINS * 4);
    int* deg  = (int*)(ws + off);              off = align256(off + (size_t)(N + 1) * 4);
    float* dinv = (float*)(ws + off);          off = align256(off + (size_t)(N + 1) * 4);
    int* pairs = (int*)(ws + off);             off = align256(off + ((size_t)nbins * BIN_CAP + 64) * 4);
    unsigned short* h = (unsigned short*)(ws + off); off = align256(off + (size_t)(N + 1) * DIM * 2);

    int nchunks = (E + CHUNK_EDGES - 1) / CHUNK_EDGES;       // 245

    hipMemsetAsync(gcur, 0, (size_t)MAX_BINS * 4, stream);
    bin_scatter_kernel<<<nchunks, SCATTER_THREADS, 0, stream>>>(ei, gcur, pairs, E, nbins);
    deg_gemm_kernel<<<nbins, 256, 0, stream>>>(x, W, pairs, gcur, deg, dinv, h, N);
    aggregate_kernel<<<nbins, 512, 0, stream>>>(h, pairs, gcur, deg, dinv, b, out, N);
}

// Round 16
// 124.124 us; speedup vs baseline: 1.0952x; 1.0202x over previous
//
#include <hip/hip_runtime.h>
#include <hip/hip_cooperative_groups.h>

namespace cg = cooperative_groups;

#define DIM 64
#define BIN_SHIFT 7                  // 128 nodes per bin
#define NODES_PER_BIN 128
#define MAX_BINS 1024                // ceil(100000/128)=782 <= 1024
#define BIN_CAP 2048                 // mean 1279, sigma ~36 -> 21-sigma margin
#define CHUNK_EDGES 4096             // fallback scatter chunk (R14)
#define SCATTER_THREADS 1024         // fallback scatter width (R14)
#define FXSCALE 65536.0f             // fixed-point scale 2^16
#define FXINV (1.0f / 65536.0f)
#define FXBIAS 524288u               // 2^19 per-term bias (|v|<8 -> term >= 0)
#define MAGIC 12582912.0f            // 1.5*2^23 RNE float->int magic
#define MAGIC_I 0x4B400000u
#define ACC_U64 33                   // u64 per node row: 32 used + 1 pad
#define FSLOTS 5                     // fused: chunk 1280 = 5 x 256

// ws layout (256-aligned), shared by both paths:
// gcur[MAX_BINS] | deg[N+1] | dinv[N+1] | pairs[nbins*BIN_CAP+64] | h[(N+1)*64] bf16
//
// Primary: ONE cooperative kernel, 782 blocks x 256 threads (4 waves),
// 4 blocks/CU = 16 waves/CU (margin: wave cap 32, VGPR cap 128, LDS 38.9/40KB).
// R15's rejection diagnosed as zero-margin occupancy (32 waves + 64 VGPR +
// 155.6KB all at limits).  Host gates on occupancy query; fallback = R14
// 4-dispatch path (126.6us, known-good).

using bf16x8 = __attribute__((ext_vector_type(8))) short;
using u16x8  = __attribute__((ext_vector_type(8))) unsigned short;
using f32x4  = __attribute__((ext_vector_type(4))) float;

__device__ __forceinline__ unsigned short f2bf(float f) {
    unsigned u = __float_as_uint(f);
    u += 0x7fffu + ((u >> 16) & 1u);     // round-to-nearest-even
    return (unsigned short)(u >> 16);
}
__device__ __forceinline__ float bf2f(unsigned short u) {
    return __uint_as_float((unsigned)u << 16);
}
__device__ __forceinline__ unsigned fxq(unsigned short bf) {   // bf16 -> biased fx
    return __float_as_uint(fmaf(bf2f(bf), FXSCALE, MAGIC)) - (MAGIC_I - FXBIAS);
}

union SmemU {
    struct { unsigned short Xs[NODES_PER_BIN * 64]; unsigned short Ws[64 * 64]; } g; // 24 KB
    int base[MAX_BINS];                                   // 4 KB
    unsigned long long acc[NODES_PER_BIN * ACC_U64];      // 33 KB
};

// ============================ FUSED (primary) ============================
__global__ __launch_bounds__(256, 4) void fused_kernel(
    const void* __restrict__ ei, const float* __restrict__ x,
    const float* __restrict__ W, const float* __restrict__ bias,
    int* __restrict__ gcur, int* __restrict__ pairs,
    unsigned short* __restrict__ h, float* __restrict__ out,
    int E, int N, int nbins, int chunk) {
    cg::grid_group grid = cg::this_grid();
    __shared__ int h1[MAX_BINS];          // hist (P0), rank counters (P1)
    __shared__ SmemU u;
    __shared__ int sdeg[NODES_PER_BIN];
    __shared__ float sdinv[NODES_PER_BIN];
    __shared__ int s_notz;

    int tid = threadIdx.x;
    int b = blockIdx.x;
    int node0 = b << BIN_SHIFT;
    int nn = min(NODES_PER_BIN, N - node0);
    int w = tid >> 6, l = tid & 63;
    int lm = l & 15, kg = l >> 4;

    // ---------------- P0: zero gcur[b], edges+hist, stage, MFMA ----------------
    if (tid == 0) { s_notz = 0; gcur[b] = 0; }
    for (int i = tid; i < nbins; i += 256) h1[i] = 0;
    __syncthreads();
    if (((const int*)ei)[2 * tid + 1] != 0) s_notz = 1;   // benign race (same value)
    __syncthreads();
    int is64 = (s_notz == 0);

    int e0 = b * chunk;
    int e1 = min(e0 + chunk, E);
    int ss[FSLOTS], dd[FSLOTS];
#pragma unroll
    for (int k = 0; k < FSLOTS; ++k) {
        int i = e0 + k * 256 + tid;
        dd[k] = -1;
        if (i < e1) {
            if (is64) {
                ss[k] = (int)((const long long*)ei)[i];
                dd[k] = (int)((const long long*)ei)[(long long)i + E];
            } else {
                ss[k] = ((const int*)ei)[i];
                dd[k] = ((const int*)ei)[i + E];
            }
            atomicAdd(&h1[dd[k] >> BIN_SHIFT], 1);
        }
    }
    // stage W (64x64 -> swizzled bf16), 2 chunks/thread
#pragma unroll
    for (int uu = 0; uu < 2; ++uu) {
        int idx = uu * 256 + tid;
        int c = idx >> 3, k0 = (idx & 7) * 8;
        float4 a = *(const float4*)&W[c * 64 + k0];
        float4 bb = *(const float4*)&W[c * 64 + k0 + 4];
        bf16x8 v;
        v[0] = (short)f2bf(a.x); v[1] = (short)f2bf(a.y);
        v[2] = (short)f2bf(a.z); v[3] = (short)f2bf(a.w);
        v[4] = (short)f2bf(bb.x); v[5] = (short)f2bf(bb.y);
        v[6] = (short)f2bf(bb.z); v[7] = (short)f2bf(bb.w);
        int byteoff = c * 128 + ((k0 * 2) ^ ((c & 7) << 4));
        *(bf16x8*)((char*)u.g.Ws + byteoff) = v;
    }
    // stage X (128x64 -> swizzled bf16), 4 chunks/thread
    const float* xbase = x + (size_t)node0 * DIM;
#pragma unroll
    for (int uu = 0; uu < 4; ++uu) {
        int idx = uu * 256 + tid;
        int r = idx >> 3, k0 = (idx & 7) * 8;
        float4 a = make_float4(0.f, 0.f, 0.f, 0.f), bb = a;
        if (r < nn) {
            a = *(const float4*)&xbase[r * DIM + k0];
            bb = *(const float4*)&xbase[r * DIM + k0 + 4];
        }
        bf16x8 v;
        v[0] = (short)f2bf(a.x); v[1] = (short)f2bf(a.y);
        v[2] = (short)f2bf(a.z); v[3] = (short)f2bf(a.w);
        v[4] = (short)f2bf(bb.x); v[5] = (short)f2bf(bb.y);
        v[6] = (short)f2bf(bb.z); v[7] = (short)f2bf(bb.w);
        int byteoff = r * 128 + ((k0 * 2) ^ ((r & 7) << 4));
        *(bf16x8*)((char*)u.g.Xs + byteoff) = v;
    }
    __syncthreads();                 // staging + hist final

    // MFMA (R13 4-wave mapping): wave w -> rows 32w..32w+31, acc in REGISTERS
    f32x4 racc[2][4] = {};
#pragma unroll
    for (int ks = 0; ks < 2; ++ks) {
        int kbyte = ks * 64 + kg * 16;
        int r0g = 32 * w + lm;
        int r1g = 32 * w + 16 + lm;
        bf16x8 a0 = *(const bf16x8*)((const char*)u.g.Xs + r0g * 128 + (kbyte ^ ((r0g & 7) << 4)));
        bf16x8 a1 = *(const bf16x8*)((const char*)u.g.Xs + r1g * 128 + (kbyte ^ ((r1g & 7) << 4)));
#pragma unroll
        for (int nt = 0; nt < 4; ++nt) {
            int ng = nt * 16 + lm;
            bf16x8 bv = *(const bf16x8*)((const char*)u.g.Ws + ng * 128 + (kbyte ^ ((ng & 7) << 4)));
            racc[0][nt] = __builtin_amdgcn_mfma_f32_16x16x32_bf16(a0, bv, racc[0][nt], 0, 0, 0);
            racc[1][nt] = __builtin_amdgcn_mfma_f32_16x16x32_bf16(a1, bv, racc[1][nt], 0, 0, 0);
        }
    }
    grid.sync();                     // SYNC1: gcur zeroed everywhere

    // ---------------- P1: reservations (overlapped) + ranks + pair writes ----------------
    int myc[4] = {0, 0, 0, 0}, ret[4] = {0, 0, 0, 0};
#pragma unroll
    for (int j = 0; j < 4; ++j) {
        int i = tid + j * 256;
        if (i < nbins) myc[j] = h1[i];
    }
    __syncthreads();                 // all count reads done
    for (int i = tid; i < nbins; i += 256) h1[i] = 0;
    __syncthreads();
#pragma unroll
    for (int j = 0; j < 4; ++j) {    // issue reservations (returns in flight)
        int i = tid + j * 256;
        if (i < nbins && myc[j]) ret[j] = atomicAdd(&gcur[i], myc[j]);
    }
    int rk[FSLOTS];
#pragma unroll
    for (int k = 0; k < FSLOTS; ++k) // ranks overlap the reservation returns
        if (dd[k] >= 0) rk[k] = atomicAdd(&h1[dd[k] >> BIN_SHIFT], 1);
#pragma unroll
    for (int j = 0; j < 4; ++j) {    // consume returns
        int i = tid + j * 256;
        if (i < nbins && myc[j]) u.base[i] = i * BIN_CAP + ret[j];
    }
    __syncthreads();                 // base + ranks visible
#pragma unroll
    for (int k = 0; k < FSLOTS; ++k) {
        if (dd[k] >= 0) {
            int bin = dd[k] >> BIN_SHIFT;
            int pos = u.base[bin] + rk[k];
            if (pos < (bin + 1) * BIN_CAP)          // overflow guard (never expected)
                pairs[pos] = (ss[k] << BIN_SHIFT) | (dd[k] & (NODES_PER_BIN - 1));
        }
    }
    grid.sync();                     // SYNC2: pairs + gcur final

    // ---------------- P2: degree + scale + write h ----------------
    int cnt = min(gcur[b], BIN_CAP);
    if (tid < NODES_PER_BIN) sdeg[tid] = 0;
    __syncthreads();
    const int* pb = pairs + b * BIN_CAP;
    for (int i = tid; i < cnt; i += 256)
        atomicAdd(&sdeg[pb[i] & (NODES_PER_BIN - 1)], 1);
    __syncthreads();
    if (tid < NODES_PER_BIN)
        sdinv[tid] = rsqrtf((float)(sdeg[tid] + 1));   // +1 self-loop
    __syncthreads();
#pragma unroll
    for (int mt = 0; mt < 2; ++mt) {
#pragma unroll
        for (int j = 0; j < 4; ++j) {   // D: row=(l>>4)*4+j, col=lm per tile
            int rl = 32 * w + 16 * mt + (l >> 4) * 4 + j;
            if (rl < nn) {
                float dv = sdinv[rl];
                size_t rowoff = (size_t)(node0 + rl) * DIM;
#pragma unroll
                for (int nt = 0; nt < 4; ++nt)
                    h[rowoff + nt * 16 + lm] = f2bf(racc[mt][nt][j] * dv);
            }
        }
    }
    grid.sync();                     // SYNC3: all h visible

    // ---------------- P3: aggregate (R13 shape, 4 waves) ----------------
    for (int i = tid; i < NODES_PER_BIN * ACC_U64; i += 256) u.acc[i] = 0ULL;
    __syncthreads();
    int g = l >> 3;                  // edge slot 0..7
    int fq = l & 7;                  // features 8*fq .. 8*fq+7
    int dummy = N << BIN_SHIFT;      // row N load is garbage but gated off

    for (int j0 = 64 * w; j0 < cnt; j0 += 256) {
        int pk[8]; bool vd[8];
#pragma unroll
        for (int uu = 0; uu < 8; ++uu) {
            int e = j0 + 8 * uu + g;
            vd[uu] = (e < cnt);
            pk[uu] = vd[uu] ? pb[e] : dummy;
        }
        u16x8 r[8];
#pragma unroll
        for (int uu = 0; uu < 8; ++uu)    // issue all 8 x 16B gathers before use
            r[uu] = *(const u16x8*)(h + (size_t)(pk[uu] >> BIN_SHIFT) * DIM + 8 * fq);
#pragma unroll
        for (int uu = 0; uu < 8; ++uu) {
            unsigned q0 = fxq(r[uu][0]), q1 = fxq(r[uu][1]);
            unsigned q2 = fxq(r[uu][2]), q3 = fxq(r[uu][3]);
            unsigned q4 = fxq(r[uu][4]), q5 = fxq(r[uu][5]);
            unsigned q6 = fxq(r[uu][6]), q7 = fxq(r[uu][7]);
            if (vd[uu]) {
                unsigned long long* ar =
                    &u.acc[(pk[uu] & (NODES_PER_BIN - 1)) * ACC_U64 + 4 * fq];
                atomicAdd(&ar[0], (unsigned long long)q0 | ((unsigned long long)q1 << 32));
                atomicAdd(&ar[1], (unsigned long long)q2 | ((unsigned long long)q3 << 32));
                atomicAdd(&ar[2], (unsigned long long)q4 | ((unsigned long long)q5 << 32));
                atomicAdd(&ar[3], (unsigned long long)q6 | ((unsigned long long)q7 << 32));
            }
        }
    }
    __syncthreads();

    // dword view: feature f (0..63) of node n at dword [n*66 + f]
    const int* accd = (const int*)u.acc;
    float bl = bias[l];
    for (int n0 = w; n0 < nn; n0 += 4) {
        int gn = node0 + n0;
        int dgn = sdeg[n0];
        float di = sdinv[n0];
        unsigned q = (unsigned)accd[n0 * (2 * ACC_U64) + l];
        int sfx = (int)(q - (unsigned)dgn * FXBIAS);        // remove per-term bias
        float sum = (float)sfx * FXINV;
        float self = bf2f(h[(size_t)gn * DIM + l]);         // pre-scaled by dinv[gn]
        out[(size_t)gn * DIM + l] = (sum + self) * di + bl;
    }
}

// ============================ FALLBACK (R14, 126.6us) ============================
__global__ __launch_bounds__(SCATTER_THREADS) void bin_scatter_kernel(
    const void* __restrict__ ei, int* __restrict__ gcur,
    int* __restrict__ pairs, int E, int nbins) {
    __shared__ int h1[MAX_BINS];
    __shared__ int h2[MAX_BINS];
    __shared__ int base[MAX_BINS];
    __shared__ int s_notz;
    int tid = threadIdx.x;
    if (tid == 0) s_notz = 0;
    for (int i = tid; i < nbins; i += SCATTER_THREADS) { h1[i] = 0; h2[i] = 0; }
    __syncthreads();
    if (((const int*)ei)[2 * tid + 1] != 0) s_notz = 1;
    __syncthreads();
    int is64 = (s_notz == 0);
    int chunk = blockIdx.x * CHUNK_EDGES;
    int ss[4], dd[4];
#pragma unroll
    for (int k = 0; k < 4; ++k) {
        int i = chunk + k * SCATTER_THREADS + tid;
        dd[k] = -1;
        if (i < E) {
            if (is64) {
                ss[k] = (int)((const long long*)ei)[i];
                dd[k] = (int)((const long long*)ei)[(long long)i + E];
            } else {
                ss[k] = ((const int*)ei)[i];
                dd[k] = ((const int*)ei)[i + E];
            }
            atomicAdd(&h1[dd[k] >> BIN_SHIFT], 1);
        }
    }
    __syncthreads();
    int myc = 0, ret = 0;
    if (tid < nbins) {
        myc = h1[tid];
        if (myc) ret = atomicAdd(&gcur[tid], myc);
    }
    int rk[4];
#pragma unroll
    for (int k = 0; k < 4; ++k)
        if (dd[k] >= 0) rk[k] = atomicAdd(&h2[dd[k] >> BIN_SHIFT], 1);
    if (myc) base[tid] = tid * BIN_CAP + ret;
    __syncthreads();
#pragma unroll
    for (int k = 0; k < 4; ++k) {
        if (dd[k] >= 0) {
            int bin = dd[k] >> BIN_SHIFT;
            int pos = base[bin] + rk[k];
            if (pos < (bin + 1) * BIN_CAP)
                pairs[pos] = (ss[k] << BIN_SHIFT) | (dd[k] & (NODES_PER_BIN - 1));
        }
    }
}

__global__ __launch_bounds__(256) void deg_gemm_kernel(
    const float* __restrict__ x, const float* __restrict__ W,
    const int* __restrict__ pairs, const int* __restrict__ gcur,
    int* __restrict__ deg, float* __restrict__ dinv,
    unsigned short* __restrict__ h, int N) {
    __shared__ unsigned short Xs[NODES_PER_BIN * 64];
    __shared__ unsigned short Ws[64 * 64];
    __shared__ int sdeg[NODES_PER_BIN];
    __shared__ float sdinv[NODES_PER_BIN];
    int tid = threadIdx.x;
    int b = blockIdx.x;
    int row0 = b << BIN_SHIFT;
    int nn = min(NODES_PER_BIN, N - row0);
    int cntb = min(gcur[b], BIN_CAP);

    if (tid < NODES_PER_BIN) sdeg[tid] = 0;
#pragma unroll
    for (int u = 0; u < 2; ++u) {
        int idx = u * 256 + tid;
        int c = idx >> 3, k0 = (idx & 7) * 8;
        float4 a = *(const float4*)&W[c * 64 + k0];
        float4 bb = *(const float4*)&W[c * 64 + k0 + 4];
        bf16x8 v;
        v[0] = (short)f2bf(a.x); v[1] = (short)f2bf(a.y);
        v[2] = (short)f2bf(a.z); v[3] = (short)f2bf(a.w);
        v[4] = (short)f2bf(bb.x); v[5] = (short)f2bf(bb.y);
        v[6] = (short)f2bf(bb.z); v[7] = (short)f2bf(bb.w);
        int byteoff = c * 128 + ((k0 * 2) ^ ((c & 7) << 4));
        *(bf16x8*)((char*)Ws + byteoff) = v;
    }
    const float* xbase = x + (size_t)row0 * DIM;
#pragma unroll
    for (int u = 0; u < 4; ++u) {
        int idx = u * 256 + tid;
        int r = idx >> 3, k0 = (idx & 7) * 8;
        float4 a = make_float4(0.f, 0.f, 0.f, 0.f), bb = a;
        if (r < nn) {
            a = *(const float4*)&xbase[r * DIM + k0];
            bb = *(const float4*)&xbase[r * DIM + k0 + 4];
        }
        bf16x8 v;
        v[0] = (short)f2bf(a.x); v[1] = (short)f2bf(a.y);
        v[2] = (short)f2bf(a.z); v[3] = (short)f2bf(a.w);
        v[4] = (short)f2bf(bb.x); v[5] = (short)f2bf(bb.y);
        v[6] = (short)f2bf(bb.z); v[7] = (short)f2bf(bb.w);
        int byteoff = r * 128 + ((k0 * 2) ^ ((r & 7) << 4));
        *(bf16x8*)((char*)Xs + byteoff) = v;
    }
    __syncthreads();
    const int* pb = pairs + b * BIN_CAP;
    for (int i = tid; i < cntb; i += 256)
        atomicAdd(&sdeg[pb[i] & (NODES_PER_BIN - 1)], 1);
    __syncthreads();
    if (tid < NODES_PER_BIN) {
        int d = sdeg[tid];
        float dv = rsqrtf((float)(d + 1));
        sdinv[tid] = dv;
        if (tid < nn) {
            deg[row0 + tid] = d;
            dinv[row0 + tid] = dv;
        }
    }
    __syncthreads();

    int w = tid >> 6, l = tid & 63;
    int lm = l & 15, kg = l >> 4;
    f32x4 acc[2][4] = {};
#pragma unroll
    for (int ks = 0; ks < 2; ++ks) {
        int kbyte = ks * 64 + kg * 16;
        int r0g = 32 * w + lm;
        int r1g = 32 * w + 16 + lm;
        bf16x8 a0 = *(const bf16x8*)((const char*)Xs + r0g * 128 + (kbyte ^ ((r0g & 7) << 4)));
        bf16x8 a1 = *(const bf16x8*)((const char*)Xs + r1g * 128 + (kbyte ^ ((r1g & 7) << 4)));
#pragma unroll
        for (int nt = 0; nt < 4; ++nt) {
            int ng = nt * 16 + lm;
            bf16x8 bv = *(const bf16x8*)((const char*)Ws + ng * 128 + (kbyte ^ ((ng & 7) << 4)));
            acc[0][nt] = __builtin_amdgcn_mfma_f32_16x16x32_bf16(a0, bv, acc[0][nt], 0, 0, 0);
            acc[1][nt] = __builtin_amdgcn_mfma_f32_16x16x32_bf16(a1, bv, acc[1][nt], 0, 0, 0);
        }
    }
#pragma unroll
    for (int mt = 0; mt < 2; ++mt) {
#pragma unroll
        for (int j = 0; j < 4; ++j) {
            int rl = 32 * w + 16 * mt + (l >> 4) * 4 + j;
            if (rl < nn) {
                float dv = sdinv[rl];
                size_t rowoff = (size_t)(row0 + rl) * DIM;
#pragma unroll
                for (int nt = 0; nt < 4; ++nt)
                    h[rowoff + nt * 16 + lm] = f2bf(acc[mt][nt][j] * dv);
            }
        }
    }
}

__global__ __launch_bounds__(512) void aggregate_kernel(
    const unsigned short* __restrict__ h, const int* __restrict__ pairs,
    const int* __restrict__ gcur, const int* __restrict__ deg,
    const float* __restrict__ dinv, const float* __restrict__ bias,
    float* __restrict__ out, int N) {
    __shared__ unsigned long long acc[NODES_PER_BIN * ACC_U64];
    int b = blockIdx.x;
    int tid = threadIdx.x;
    int cnt = min(gcur[b], BIN_CAP);
    int node0 = b << BIN_SHIFT;
    int nn = min(NODES_PER_BIN, N - node0);

    for (int i = tid; i < NODES_PER_BIN * ACC_U64; i += 512) acc[i] = 0ULL;
    __syncthreads();

    int wave = tid >> 6, lane = tid & 63;
    int g = lane >> 3;
    int fq = lane & 7;
    const int* pb = pairs + b * BIN_CAP;
    int dummy = N << BIN_SHIFT;

    for (int j0 = 64 * wave; j0 < cnt; j0 += 512) {
        int pk[8]; bool vd[8];
#pragma unroll
        for (int u = 0; u < 8; ++u) {
            int e = j0 + 8 * u + g;
            vd[u] = (e < cnt);
            pk[u] = vd[u] ? pb[e] : dummy;
        }
        u16x8 r[8];
#pragma unroll
        for (int u = 0; u < 8; ++u)
            r[u] = *(const u16x8*)(h + (size_t)(pk[u] >> BIN_SHIFT) * DIM + 8 * fq);
#pragma unroll
        for (int u = 0; u < 8; ++u) {
            unsigned q0 = fxq(r[u][0]), q1 = fxq(r[u][1]);
            unsigned q2 = fxq(r[u][2]), q3 = fxq(r[u][3]);
            unsigned q4 = fxq(r[u][4]), q5 = fxq(r[u][5]);
            unsigned q6 = fxq(r[u][6]), q7 = fxq(r[u][7]);
            if (vd[u]) {
                unsigned long long* ar =
                    &acc[(pk[u] & (NODES_PER_BIN - 1)) * ACC_U64 + 4 * fq];
                atomicAdd(&ar[0], (unsigned long long)q0 | ((unsigned long long)q1 << 32));
                atomicAdd(&ar[1], (unsigned long long)q2 | ((unsigned long long)q3 << 32));
                atomicAdd(&ar[2], (unsigned long long)q4 | ((unsigned long long)q5 << 32));
                atomicAdd(&ar[3], (unsigned long long)q6 | ((unsigned long long)q7 << 32));
            }
        }
    }
    __syncthreads();

    const int* accd = (const int*)acc;
    float bl = bias[lane];
    for (int n0 = wave; n0 < nn; n0 += 8) {
        int gn = node0 + n0;
        int dgn = deg[gn];
        float di = dinv[gn];
        unsigned q = (unsigned)accd[n0 * (2 * ACC_U64) + lane];
        int sfx = (int)(q - (unsigned)dgn * FXBIAS);
        float sum = (float)sfx * FXINV;
        float self = bf2f(h[(size_t)gn * DIM + lane]);
        out[(size_t)gn * DIM + lane] = (sum + self) * di + bl;
    }
}

extern "C" void kernel_launch(void* const* d_in, const int* in_sizes, int n_in,
                              void* d_out, int out_size, void* d_ws, size_t ws_size,
                              hipStream_t stream) {
    const float* x = (const float*)d_in[0];
    const void* ei = d_in[1];
    const float* W = (const float*)d_in[2];
    const float* bias = (const float*)d_in[3];
    float* out = (float*)d_out;

    int N = in_sizes[0] / DIM;   // 100000
    int E = in_sizes[1] / 2;     // 1000000
    int nbins = (N + NODES_PER_BIN - 1) >> BIN_SHIFT;   // 782
    int chunk = ((E + nbins - 1) / nbins + 255) & ~255; // 1280 = 5*256

    char* ws = (char*)d_ws;
    auto align256 = [](size_t v) { return (v + 255) & ~(size_t)255; };
    size_t off = 0;
    int* gcur = (int*)(ws + off);              off = align256(off + (size_t)MAX_BINS * 4);
    int* deg  = (int*)(ws + off);              off = align256(off + (size_t)(N + 1) * 4);
    float* dinv = (float*)(ws + off);          off = align256(off + (size_t)(N + 1) * 4);
    int* pairs = (int*)(ws + off);             off = align256(off + ((size_t)nbins * BIN_CAP + 64) * 4);
    unsigned short* h = (unsigned short*)(ws + off); off = align256(off + (size_t)(N + 1) * DIM * 2);

    // Host-side capacity gate (host-only queries, cached; capture-safe).
    static int s_use_coop = -1;
    if (s_use_coop < 0) {
        int dev = 0, coop = 0, ncu = 0, maxb = 0;
        (void)hipGetDevice(&dev);
        (void)hipDeviceGetAttribute(&coop, hipDeviceAttributeCooperativeLaunch, dev);
        (void)hipDeviceGetAttribute(&ncu, hipDeviceAttributeMultiprocessorCount, dev);
        (void)hipOccupancyMaxActiveBlocksPerMultiprocessor(&maxb, (const void*)fused_kernel, 256, 0);
        s_use_coop = (coop && (long long)maxb * ncu >= nbins) ? 1 : 0;
    }

    if (s_use_coop) {
        void* args[] = {
            (void*)&ei, (void*)&x, (void*)&W, (void*)&bias,
            (void*)&gcur, (void*)&pairs, (void*)&h, (void*)&out,
            (void*)&E, (void*)&N, (void*)&nbins, (void*)&chunk
        };
        hipError_t err = hipLaunchCooperativeKernel((const void*)fused_kernel,
                                                    dim3(nbins), dim3(256), args, 0, stream);
        if (err == hipSuccess) return;
        s_use_coop = 0;              // fall through to the proven path
    }

    int nchunks = (E + CHUNK_EDGES - 1) / CHUNK_EDGES;       // 245
    hipMemsetAsync(gcur, 0, (size_t)MAX_BINS * 4, stream);
    bin_scatter_kernel<<<nchunks, SCATTER_THREADS, 0, stream>>>(ei, gcur, pairs, E, nbins);
    deg_gemm_kernel<<<nbins, 256, 0, stream>>>(x, W, pairs, gcur, deg, dinv, h, N);
    aggregate_kernel<<<nbins, 512, 0, stream>>>(h, pairs, gcur, deg, dinv, bias, out, N);
}